// Round 4
// baseline (58.517 us; speedup 1.0000x reference)
//
#include <hip/hip_runtime.h>
#include <hip/hip_cooperative_groups.h>

namespace cg = cooperative_groups;

#define NB    64
#define NPT   8192
#define GSZ   128
#define TPB   512
#define BPB   16                        // blocks per batch
#define NBLK  (NB * BPB)                // 1024 blocks = full chip, 8 waves/EU
#define NTHR  (NBLK * TPB)              // 524288 = one thread per point
#define OUT4  (3 * GSZ * GSZ * NB / 4)  // 786432 float4s

// Per-point permutohedral computation. Bitwise-replicates XLA-CPU f32
// (verified absmax == 0.0 rounds 1-3):
//  - pc = x*190.0f           (single IEEE mul)
//  - elevated = E @ pc       (Eigen gemm: FMA chain, k ascending)
//  - u = rint(ev/3)          (IEEE div, round-half-even)
// Integer tail refactored (exactly): output bin i = u0 - min_batch(u0),
// window c<384 <=> i<128; rank only enters via the remainder fixup of u.
__device__ __forceinline__ void compute_u(const float* __restrict__ x, int b, int n,
                                          int& u0o, int& u1o) {
    const float s6 = (float)2.449489742783178098197284074705891391989;
    const float ca = 2.0f / s6;
    const float cb = -1.0f / s6;
    const float* xb = x + (size_t)b * 6 * NPT + n;
    float p0 = xb[0 * NPT] * 190.0f;
    float p1 = xb[1 * NPT] * 190.0f;
    float p2 = xb[2 * NPT] * 190.0f;
    float ev0 = __builtin_fmaf(cb, p2, __builtin_fmaf(cb, p1, ca * p0));
    float ev1 = __builtin_fmaf(cb, p2, __builtin_fmaf(ca, p1, cb * p0));
    float ev2 = __builtin_fmaf(ca, p2, __builtin_fmaf(cb, p1, cb * p0));
    float q0 = ev0 / 3.0f, q1 = ev1 / 3.0f, q2 = ev2 / 3.0f;
    float rg0 = rintf(q0), rg1 = rintf(q1), rg2 = rintf(q2);  // round-half-even
    int u0 = (int)rg0, u1 = (int)rg1, u2 = (int)rg2;
    float e0 = ev0 - rg0 * 3.0f;
    float e1 = ev1 - rg1 * 3.0f;
    float e2 = ev2 - rg2 * 3.0f;
    // stable descending argsort -> ranks (only dims 0,1 needed downstream)
    int rk0 = (int)(e1 > e0) + (int)(e2 > e0);
    int rk1 = (int)(e0 > e1) + (int)(e0 == e1) + (int)(e2 > e1);
    int rs = u0 + u1 + u2;   // == sum(greedy)/3 exactly
    if (rs > 0) {
        if (rk0 >= 3 - rs) u0 -= 1;
        if (rk1 >= 3 - rs) u1 -= 1;
    } else if (rs < 0) {
        if (rk0 < -rs) u0 += 1;
        if (rk1 < -rs) u1 += 1;
    }
    u0o = u0; u1o = u1;
}

// Single cooperative kernel: zero out + keys in regs + per-block min -> bm,
// grid sync, per-batch min of 16 block minima, scatter from regs.
__global__ __launch_bounds__(TPB, 8) void kcoop(const float* __restrict__ x,
                                                float* __restrict__ out,
                                                int* __restrict__ bm) {
    const int bid = blockIdx.x, t = threadIdx.x;
    const int gid = bid * TPB + t;

    // zero the output (grid-strided, decoupled from batch mapping)
    float4* o4 = (float4*)out;
    const float4 z4 = make_float4(0.f, 0.f, 0.f, 0.f);
    o4[gid] = z4;
    int g2 = gid + NTHR;
    if (g2 < OUT4) o4[g2] = z4;

    const int b = bid >> 4;              // BPB = 16
    const int n = ((bid & 15) << 9) | t; // 512 points per block, coalesced
    int u0, u1;
    compute_u(x, b, n, u0, u1);

    // block-min of (u0,u1)
    int m0 = u0, m1 = u1;
    for (int o = 32; o; o >>= 1) {
        m0 = min(m0, __shfl_down(m0, o));
        m1 = min(m1, __shfl_down(m1, o));
    }
    __shared__ int red0[8], red1[8];
    if ((t & 63) == 0) { red0[t >> 6] = m0; red1[t >> 6] = m1; }
    __syncthreads();
    if (t == 0) {
        int a0 = red0[0], a1 = red1[0];
#pragma unroll
        for (int i = 1; i < TPB / 64; ++i) { a0 = min(a0, red0[i]); a1 = min(a1, red1[i]); }
        bm[bid * 2 + 0] = a0;
        bm[bid * 2 + 1] = a1;
    }

    cg::this_grid().sync();

    // per-batch offset = min over the batch's 16 block minima
    __shared__ int osh[2];
    if (t < 64) {
        int a0 = 0x7fffffff, a1 = 0x7fffffff;
        if (t < BPB) { a0 = bm[((b << 4) + t) * 2 + 0]; a1 = bm[((b << 4) + t) * 2 + 1]; }
        for (int o = 8; o; o >>= 1) {
            a0 = min(a0, __shfl_down(a0, o));
            a1 = min(a1, __shfl_down(a1, o));
        }
        if (t == 0) { osh[0] = a0; osh[1] = a1; }
    }
    __syncthreads();

    // scatter (keys still in registers; i,j >= 0 always)
    const int i = u0 - osh[0], j = u1 - osh[1];
    if (i < GSZ && j < GSZ) {
        const float* xb = x + (size_t)b * 6 * NPT + n;
        float* o = out + (size_t)b * 3 * GSZ * GSZ + (size_t)i * GSZ + j;
        atomicAdd(o + 0 * GSZ * GSZ, xb[3 * NPT]);
        atomicAdd(o + 1 * GSZ * GSZ, xb[4 * NPT]);
        atomicAdd(o + 2 * GSZ * GSZ, xb[5 * NPT]);
    }
}

extern "C" void kernel_launch(void* const* d_in, const int* in_sizes, int n_in,
                              void* d_out, int out_size, void* d_ws, size_t ws_size,
                              hipStream_t stream) {
    const float* x = (const float*)d_in[0];
    float* out = (float*)d_out;
    int* bm = (int*)d_ws;  // 2048 ints
    void* args[] = {(void*)&x, (void*)&out, (void*)&bm};
    hipLaunchCooperativeKernel(kcoop, dim3(NBLK), dim3(TPB), args, 0, stream);
}